// Round 2
// baseline (553.858 us; speedup 1.0000x reference)
//
#include <hip/hip_runtime.h>
#include <hip/hip_bf16.h>

// MultiheadBlockAttention: B=4, S=512, NB=32, D=512, H=8, dh=64.
// One WG (8 waves) per (b,s). Wave h == head h end-to-end:
//   - projections: wave h computes Q/K/V cols 64h..64h+63 (its own head slice),
//     results stay in registers as packed bf16 C/D fragments (no shared QKV LDS).
//   - attention: S^T = K*Q^T (swapped) so softmax is within-lane + 1 shfl_xor(32);
//     P and V feed PV MFMAs via cross-half shfl + cndmask (no LDS);
//     only Q/K transpose through a per-wave 4.3KB scratch (barrier-free).
// LDS 66 KB -> 2 WG/CU (4 waves/SIMD), attention phase has zero barriers.

#define NBD (32 * 512)
#define XS_STRIDE 516  // shorts per X row = 1032 B (2-way bank-free at b64 reads)
#define SC_STRIDE 68   // shorts per scratch row = 136 B (2-way bank-free)

typedef __bf16 bf16x8 __attribute__((ext_vector_type(8)));
typedef float f32x16 __attribute__((ext_vector_type(16)));

__device__ __forceinline__ unsigned f2b(float f) {
  union { float f; unsigned u; } v;
  v.f = f;
  return (v.u + 0x7fffu + ((v.u >> 16) & 1u)) >> 16;
}

__device__ __forceinline__ f32x16 mfma32(uint4 a, uint4 b, f32x16 c) {
  union { uint4 u; bf16x8 v; } ua, ub;
  ua.u = a;
  ub.u = b;
  return __builtin_amdgcn_mfma_f32_32x32x16_bf16(ua.v, ub.v, c, 0, 0, 0);
}

// two ds_read_b64 (base may be only 8-aligned; compiler can't fuse to b128)
__device__ __forceinline__ uint4 ld_lds_64x2(const unsigned short* p, unsigned byteoff) {
  const char* c = (const char*)p;
  uint2 lo = *(const uint2*)(c + byteoff);
  uint2 hi = *(const uint2*)(c + byteoff + 8);
  uint4 r;
  r.x = lo.x; r.y = lo.y; r.z = hi.x; r.w = hi.y;
  return r;
}

// Convert wq|wk|wv (each 512x512 f32) to bf16 into ws.
__global__ void wconv_kernel(const float* __restrict__ wq,
                             const float* __restrict__ wk,
                             const float* __restrict__ wv,
                             unsigned short* __restrict__ out) {
  const int i = blockIdx.x * blockDim.x + threadIdx.x;  // 0..65535
  const float* src[3] = {wq, wk, wv};
#pragma unroll
  for (int m = 0; m < 3; ++m) {
    float4 f = ((const float4*)src[m])[i];
    ushort4 o;
    o.x = (unsigned short)f2b(f.x);
    o.y = (unsigned short)f2b(f.y);
    o.z = (unsigned short)f2b(f.z);
    o.w = (unsigned short)f2b(f.w);
    ((ushort4*)out)[m * 65536 + i] = o;
  }
}

__global__ __launch_bounds__(512, 4)
void mhba_kernel(const float* __restrict__ q_in, const float* __restrict__ k_in,
                 const float* __restrict__ v_in, const float* __restrict__ mask,
                 const float* __restrict__ bq, const float* __restrict__ bk,
                 const float* __restrict__ bv,
                 const unsigned short* __restrict__ wbf,  // [3][512][512] bf16
                 float* __restrict__ out_attn,            // [B,S,NB,D]
                 float* __restrict__ out_w) {             // [B,H,S,NB,NB]
  __shared__ unsigned short Xs[32 * XS_STRIDE];      // 33024 B
  __shared__ unsigned short SCR[8][32 * SC_STRIDE];  // 34816 B (per-wave 4352 B)

  const int bs = blockIdx.x;    // b = bs>>9, s = bs&511
  const int tid = threadIdx.x;  // 0..511
  const int lane = tid & 63;
  const int h = tid >> 6;       // wave == head
  const int l31 = lane & 31;
  const int half = lane >> 5;

  const float* srcG[3] = {q_in, k_in, v_in};
  const float* biasG[3] = {bq, bk, bv};

  // packed bf16 C/D fragments: P[m][tile][q] holds rows (n(2q), n(2q+1)) of
  // column 64h + t*32 + l31;  n(r) = (r&3) + 8*(r>>2) + 4*half.
  unsigned P[3][2][8];

  // ---------------- projections (m: 0=Q, 1=K, 2=V) ----------------
#pragma unroll
  for (int m = 0; m < 3; ++m) {
    __syncthreads();  // protect Xs from previous iteration's readers
    const float4* src4 = (const float4*)(srcG[m] + (size_t)bs * NBD);
#pragma unroll
    for (int i = 0; i < 8; ++i) {
      const int idx4 = i * 512 + tid;  // 128 float4 per row
      float4 f = src4[idx4];
      const int n = idx4 >> 7;
      const int k4 = idx4 & 127;
      uint2 u;
      u.x = f2b(f.x) | (f2b(f.y) << 16);
      u.y = f2b(f.z) | (f2b(f.w) << 16);
      *(uint2*)((char*)Xs + (n * (XS_STRIDE * 2) + k4 * 8)) = u;
    }
    __syncthreads();

    const unsigned short* wmat = wbf + (size_t)m * (512 * 512);
#pragma unroll
    for (int t = 0; t < 2; ++t) {
      const int col = h * 64 + t * 32 + l31;  // output feature == weight row
      const uint4* wrow = (const uint4*)(wmat + (size_t)col * 512);
      const unsigned abase = (unsigned)(l31 * (XS_STRIDE * 2) + half * 16);
      f32x16 acc0, acc1;
#pragma unroll
      for (int r = 0; r < 16; ++r) { acc0[r] = 0.0f; acc1[r] = 0.0f; }
#pragma unroll 4
      for (int i = 0; i < 16; ++i) {
        uint4 a0 = ld_lds_64x2(Xs, abase + (unsigned)(2 * i) * 32);
        uint4 b0 = wrow[4 * i + half];
        uint4 a1 = ld_lds_64x2(Xs, abase + (unsigned)(2 * i + 1) * 32);
        uint4 b1 = wrow[4 * i + 2 + half];
        acc0 = mfma32(a0, b0, acc0);
        acc1 = mfma32(a1, b1, acc1);
      }
      const float bias = biasG[m][col];
#pragma unroll
      for (int q = 0; q < 8; ++q) {
        float c0 = acc0[2 * q] + acc1[2 * q] + bias;
        float c1 = acc0[2 * q + 1] + acc1[2 * q + 1] + bias;
        P[m][t][q] = f2b(c0) | (f2b(c1) << 16);
      }
    }
  }

  // ---------------- attention (barrier-free, per-wave) ----------------
  unsigned short* scr = &SCR[h][0];

  // K -> scratch (row-major [m-row][64 feat]), read A-frags (row l31, 8 feats)
#pragma unroll
  for (int t = 0; t < 2; ++t)
#pragma unroll
    for (int r = 0; r < 16; ++r) {
      const int nn = (r & 3) + 8 * (r >> 2) + 4 * half;
      scr[nn * SC_STRIDE + t * 32 + l31] =
          (unsigned short)(P[1][t][r >> 1] >> ((r & 1) * 16));
    }
  uint4 KA[4];
#pragma unroll
  for (int kk = 0; kk < 4; ++kk)
    KA[kk] = ld_lds_64x2(scr, (unsigned)(l31 * (SC_STRIDE * 2) + kk * 32 + half * 16));

  // Q -> scratch (overwrites K; same-wave DS ordering guarantees KA reads done)
#pragma unroll
  for (int t = 0; t < 2; ++t)
#pragma unroll
    for (int r = 0; r < 16; ++r) {
      const int nn = (r & 3) + 8 * (r >> 2) + 4 * half;
      scr[nn * SC_STRIDE + t * 32 + l31] =
          (unsigned short)(P[0][t][r >> 1] >> ((r & 1) * 16));
    }
  uint4 QB[4];
#pragma unroll
  for (int kk = 0; kk < 4; ++kk)
    QB[kk] = ld_lds_64x2(scr, (unsigned)(l31 * (SC_STRIDE * 2) + kk * 32 + half * 16));

  // S^T = K * Q^T : C/D lane l31 = query row n, regs = key idx m
  f32x16 lg;
#pragma unroll
  for (int r = 0; r < 16; ++r) lg[r] = 0.0f;
#pragma unroll
  for (int kk = 0; kk < 4; ++kk) lg = mfma32(KA[kk], QB[kk], lg);

  // softmax over m (16 regs + cross-half), additive mask[m]
  const float4* mask4 = (const float4*)(mask + (size_t)bs * 32);
  float4 mk4[4];
#pragma unroll
  for (int q = 0; q < 4; ++q) mk4[q] = mask4[2 * q + half];
  float x[16];
#pragma unroll
  for (int r = 0; r < 16; ++r) {
    const float* mkp = (const float*)&mk4[r >> 2];
    x[r] = lg[r] * 0.125f + mkp[r & 3];
  }
  float mx = x[0];
#pragma unroll
  for (int r = 1; r < 16; ++r) mx = fmaxf(mx, x[r]);
  mx = fmaxf(mx, __shfl_xor(mx, 32));
  float w[16], ss = 0.0f;
#pragma unroll
  for (int r = 0; r < 16; ++r) {
    w[r] = __expf(x[r] - mx);
    ss += w[r];
  }
  ss += __shfl_xor(ss, 32);
  const float inv = __frcp_rn(ss);
#pragma unroll
  for (int r = 0; r < 16; ++r) w[r] *= inv;

  // attn_weight: lane row n=l31; float4 per q at m = 8q + 4*half
  const int b = bs >> 9;
  const int s = bs & 511;
  float* wout = out_w + ((size_t)((b * 8 + h) * 512 + s)) * 1024 + l31 * 32 + 4 * half;
#pragma unroll
  for (int q = 0; q < 4; ++q) {
    float4 o;
    o.x = w[4 * q];
    o.y = w[4 * q + 1];
    o.z = w[4 * q + 2];
    o.w = w[4 * q + 3];
    *(float4*)(wout + 8 * q) = o;
  }

  // P packed: PP[q] = rows (m(2q), m(2q)+1) bf16
  unsigned PP[8], PS[8];
#pragma unroll
  for (int q = 0; q < 8; ++q) {
    PP[q] = f2b(w[2 * q]) | (f2b(w[2 * q + 1]) << 16);
    PS[q] = __shfl_xor(PP[q], 32);
  }
  unsigned VS[2][8];
#pragma unroll
  for (int t = 0; t < 2; ++t)
#pragma unroll
    for (int q = 0; q < 8; ++q) VS[t][q] = __shfl_xor(P[2][t][q], 32);

  // O = P * V : A-frag from PP/PS, B-frag from VP/VS (cross-half cndmask select)
  f32x16 o0, o1;
#pragma unroll
  for (int r = 0; r < 16; ++r) { o0[r] = 0.0f; o1[r] = 0.0f; }
#pragma unroll
  for (int kk = 0; kk < 2; ++kk) {
    uint4 pa;
    pa.x = half ? PS[4 * kk + 2] : PP[4 * kk + 0];
    pa.y = half ? PS[4 * kk + 3] : PP[4 * kk + 1];
    pa.z = half ? PP[4 * kk + 2] : PS[4 * kk + 0];
    pa.w = half ? PP[4 * kk + 3] : PS[4 * kk + 1];
    uint4 vb0, vb1;
    vb0.x = half ? VS[0][4 * kk + 2] : P[2][0][4 * kk + 0];
    vb0.y = half ? VS[0][4 * kk + 3] : P[2][0][4 * kk + 1];
    vb0.z = half ? P[2][0][4 * kk + 2] : VS[0][4 * kk + 0];
    vb0.w = half ? P[2][0][4 * kk + 3] : VS[0][4 * kk + 1];
    vb1.x = half ? VS[1][4 * kk + 2] : P[2][1][4 * kk + 0];
    vb1.y = half ? VS[1][4 * kk + 3] : P[2][1][4 * kk + 1];
    vb1.z = half ? P[2][1][4 * kk + 2] : VS[1][4 * kk + 0];
    vb1.w = half ? P[2][1][4 * kk + 3] : VS[1][4 * kk + 1];
    o0 = mfma32(pa, vb0, o0);
    o1 = mfma32(pa, vb1, o1);
  }

  // output: C/D lane col d = t*32+l31 of head h, rows n in regs
  float* obase = out_attn + (size_t)bs * NBD + h * 64 + l31;
#pragma unroll
  for (int r = 0; r < 16; ++r) {
    const int n = (r & 3) + 8 * (r >> 2) + 4 * half;
    obase[n * 512] = o0[r];
    obase[n * 512 + 32] = o1[r];
  }
}

extern "C" void kernel_launch(void* const* d_in, const int* in_sizes, int n_in,
                              void* d_out, int out_size, void* d_ws, size_t ws_size,
                              hipStream_t stream) {
  const float* q    = (const float*)d_in[0];
  const float* k    = (const float*)d_in[1];
  const float* v    = (const float*)d_in[2];
  const float* mask = (const float*)d_in[3];
  const float* wq   = (const float*)d_in[4];
  const float* bq   = (const float*)d_in[5];
  const float* wk   = (const float*)d_in[6];
  const float* bk   = (const float*)d_in[7];
  const float* wv   = (const float*)d_in[8];
  const float* bv   = (const float*)d_in[9];

  unsigned short* wbf = (unsigned short*)d_ws;  // 3*512*512 bf16 = 1.5 MB
  float* out_attn = (float*)d_out;
  float* out_w = out_attn + (size_t)4 * 512 * 32 * 512;

  wconv_kernel<<<256, 256, 0, stream>>>(wq, wk, wv, wbf);
  mhba_kernel<<<2048, 512, 0, stream>>>(q, k, v, mask, bq, bk, bv, wbf,
                                        out_attn, out_w);
}

// Round 3
// 459.264 us; speedup vs baseline: 1.2060x; 1.2060x over previous
//
#include <hip/hip_runtime.h>
#include <hip/hip_bf16.h>

// MultiheadBlockAttention: B=4, S=512, NB=32, D=512, H=8, dh=64.
// One WG (8 waves) per (b,s). Wave h == head h end-to-end.
// R3: register-diet version of R2 (which spilled ~770MB of scratch traffic
// at the launch_bounds(512,4) 128-reg cap):
//   - K projection writes bf16 directly to per-wave LDS scratch (never in regs)
//   - PV cross-half shuffles inlined (transient, not 24 persistent regs)
//   - out_w transposed through scratch -> 256B-contiguous coalesced stores
// LDS 66 KB -> 2 WG/CU (4 waves/SIMD); attention phase barrier-free.

#define NBD (32 * 512)
#define XS_STRIDE 516  // shorts per X row = 1032 B
#define SC_STRIDE 68   // shorts per scratch row = 136 B

typedef __bf16 bf16x8 __attribute__((ext_vector_type(8)));
typedef float f32x16 __attribute__((ext_vector_type(16)));

__device__ __forceinline__ unsigned f2b(float f) {
  union { float f; unsigned u; } v;
  v.f = f;
  return (v.u + 0x7fffu + ((v.u >> 16) & 1u)) >> 16;
}

__device__ __forceinline__ f32x16 mfma32(uint4 a, uint4 b, f32x16 c) {
  union { uint4 u; bf16x8 v; } ua, ub;
  ua.u = a;
  ub.u = b;
  return __builtin_amdgcn_mfma_f32_32x32x16_bf16(ua.v, ub.v, c, 0, 0, 0);
}

// two ds_read_b64 (8-aligned base)
__device__ __forceinline__ uint4 ld_lds_64x2(const unsigned short* p, unsigned byteoff) {
  const char* c = (const char*)p;
  uint2 lo = *(const uint2*)(c + byteoff);
  uint2 hi = *(const uint2*)(c + byteoff + 8);
  uint4 r;
  r.x = lo.x; r.y = lo.y; r.z = hi.x; r.w = hi.y;
  return r;
}

__global__ void wconv_kernel(const float* __restrict__ wq,
                             const float* __restrict__ wk,
                             const float* __restrict__ wv,
                             unsigned short* __restrict__ out) {
  const int i = blockIdx.x * blockDim.x + threadIdx.x;  // 0..65535
  const float* src[3] = {wq, wk, wv};
#pragma unroll
  for (int m = 0; m < 3; ++m) {
    float4 f = ((const float4*)src[m])[i];
    ushort4 o;
    o.x = (unsigned short)f2b(f.x);
    o.y = (unsigned short)f2b(f.y);
    o.z = (unsigned short)f2b(f.z);
    o.w = (unsigned short)f2b(f.w);
    ((ushort4*)out)[m * 65536 + i] = o;
  }
}

__global__ __launch_bounds__(512, 4)
void mhba_kernel(const float* __restrict__ q_in, const float* __restrict__ k_in,
                 const float* __restrict__ v_in, const float* __restrict__ mask,
                 const float* __restrict__ bq, const float* __restrict__ bk,
                 const float* __restrict__ bv,
                 const unsigned short* __restrict__ wbf,  // [3][512][512] bf16
                 float* __restrict__ out_attn,            // [B,S,NB,D]
                 float* __restrict__ out_w) {             // [B,H,S,NB,NB]
  __shared__ unsigned short Xs[32 * XS_STRIDE];      // 33024 B
  __shared__ unsigned short SCR[8][32 * SC_STRIDE];  // 34816 B (4352 B/wave)

  const int bs = blockIdx.x;    // b = bs>>9, s = bs&511
  const int tid = threadIdx.x;  // 0..511
  const int lane = tid & 63;
  const int h = tid >> 6;       // wave == head
  const int l31 = lane & 31;
  const int half = lane >> 5;

  const float* srcG[3] = {q_in, k_in, v_in};
  const float* biasG[3] = {bq, bk, bv};
  unsigned short* scr = &SCR[h][0];

  // Q and V packed bf16 C/D fragments (column 64h + t*32 + l31, rows in regs)
  unsigned QP[2][8], VP[2][8];

  // ---------------- projections (m: 0=Q, 1=K, 2=V) ----------------
#pragma unroll
  for (int m = 0; m < 3; ++m) {
    __syncthreads();  // protect Xs from previous iteration's readers
    const float4* src4 = (const float4*)(srcG[m] + (size_t)bs * NBD);
#pragma unroll
    for (int i = 0; i < 8; ++i) {
      const int idx4 = i * 512 + tid;  // 128 float4 per row
      float4 f = src4[idx4];
      const int n = idx4 >> 7;
      const int k4 = idx4 & 127;
      uint2 u;
      u.x = f2b(f.x) | (f2b(f.y) << 16);
      u.y = f2b(f.z) | (f2b(f.w) << 16);
      *(uint2*)((char*)Xs + (n * (XS_STRIDE * 2) + k4 * 8)) = u;
    }
    __syncthreads();

    const unsigned short* wmat = wbf + (size_t)m * (512 * 512);
#pragma unroll
    for (int t = 0; t < 2; ++t) {
      const int col = h * 64 + t * 32 + l31;  // output feature == weight row
      const uint4* wrow = (const uint4*)(wmat + (size_t)col * 512);
      const unsigned abase = (unsigned)(l31 * (XS_STRIDE * 2) + half * 16);
      f32x16 acc0, acc1;
#pragma unroll
      for (int r = 0; r < 16; ++r) { acc0[r] = 0.0f; acc1[r] = 0.0f; }
#pragma unroll 4
      for (int i = 0; i < 16; ++i) {
        uint4 a0 = ld_lds_64x2(Xs, abase + (unsigned)(2 * i) * 32);
        uint4 b0 = wrow[4 * i + half];
        uint4 a1 = ld_lds_64x2(Xs, abase + (unsigned)(2 * i + 1) * 32);
        uint4 b1 = wrow[4 * i + 2 + half];
        acc0 = mfma32(a0, b0, acc0);
        acc1 = mfma32(a1, b1, acc1);
      }
      const float bias = biasG[m][col];
      if (m == 1) {
        // K -> scratch directly: row nn = key idx, col = feature
#pragma unroll
        for (int r = 0; r < 16; ++r) {
          const int nn = (r & 3) + 8 * (r >> 2) + 4 * half;
          scr[nn * SC_STRIDE + t * 32 + l31] =
              (unsigned short)f2b(acc0[r] + acc1[r] + bias);
        }
      } else if (m == 0) {
#pragma unroll
        for (int q = 0; q < 8; ++q)
          QP[t][q] = f2b(acc0[2 * q] + acc1[2 * q] + bias) |
                     (f2b(acc0[2 * q + 1] + acc1[2 * q + 1] + bias) << 16);
      } else {
#pragma unroll
        for (int q = 0; q < 8; ++q)
          VP[t][q] = f2b(acc0[2 * q] + acc1[2 * q] + bias) |
                     (f2b(acc0[2 * q + 1] + acc1[2 * q + 1] + bias) << 16);
      }
    }
  }

  // ---------------- attention (barrier-free, per-wave) ----------------
  // K A-frags from scratch
  uint4 KA[4];
#pragma unroll
  for (int kk = 0; kk < 4; ++kk)
    KA[kk] = ld_lds_64x2(scr, (unsigned)(l31 * (SC_STRIDE * 2) + kk * 32 + half * 16));

  // Q -> scratch (overwrites K; per-wave program order keeps KA reads safe)
#pragma unroll
  for (int t = 0; t < 2; ++t)
#pragma unroll
    for (int r = 0; r < 16; ++r) {
      const int nn = (r & 3) + 8 * (r >> 2) + 4 * half;
      scr[nn * SC_STRIDE + t * 32 + l31] =
          (unsigned short)(QP[t][r >> 1] >> ((r & 1) * 16));
    }
  uint4 QB[4];
#pragma unroll
  for (int kk = 0; kk < 4; ++kk)
    QB[kk] = ld_lds_64x2(scr, (unsigned)(l31 * (SC_STRIDE * 2) + kk * 32 + half * 16));

  // S^T = K * Q^T : lane = query n, regs = key m
  f32x16 lg;
#pragma unroll
  for (int r = 0; r < 16; ++r) lg[r] = 0.0f;
#pragma unroll
  for (int kk = 0; kk < 4; ++kk) lg = mfma32(KA[kk], QB[kk], lg);

  // softmax over m (16 regs + cross-half), additive mask[m]
  const float4* mask4 = (const float4*)(mask + (size_t)bs * 32);
  float4 mk4[4];
#pragma unroll
  for (int q = 0; q < 4; ++q) mk4[q] = mask4[2 * q + half];
  float x[16];
#pragma unroll
  for (int r = 0; r < 16; ++r) {
    const float* mkp = (const float*)&mk4[r >> 2];
    x[r] = lg[r] * 0.125f + mkp[r & 3];
  }
  float mx = x[0];
#pragma unroll
  for (int r = 1; r < 16; ++r) mx = fmaxf(mx, x[r]);
  mx = fmaxf(mx, __shfl_xor(mx, 32));
  float w[16], ss = 0.0f;
#pragma unroll
  for (int r = 0; r < 16; ++r) {
    w[r] = __expf(x[r] - mx);
    ss += w[r];
  }
  ss += __shfl_xor(ss, 32);
  const float inv = __frcp_rn(ss);
#pragma unroll
  for (int r = 0; r < 16; ++r) w[r] *= inv;

  // pack P for PV
  unsigned PP[8];
#pragma unroll
  for (int q = 0; q < 8; ++q)
    PP[q] = f2b(w[2 * q]) | (f2b(w[2 * q + 1]) << 16);

  // out_w: transpose w through scratch (f32 view), then 256B-coalesced stores.
  // Fence: scratch was just read as u16 (QB); f32 writes must not reorder (TBAA).
  asm volatile("" ::: "memory");
  float* scrF = (float*)scr;  // 32 rows x 33 floats = 4224 B <= 4352
#pragma unroll
  for (int r = 0; r < 16; ++r) {
    const int mm = (r & 3) + 8 * (r >> 2) + 4 * half;
    scrF[l31 * 33 + mm] = w[r];  // [query n=l31][key mm]
  }
  const int b = bs >> 9;
  const int s = bs & 511;
  float* wout = out_w + ((size_t)((b * 8 + h) * 512 + s)) * 1024;
#pragma unroll
  for (int j = 0; j < 16; ++j) {
    const int n = 2 * j + half;
    wout[n * 32 + l31] = scrF[n * 33 + l31];  // 64 lanes = 256B contiguous
  }

  // O = P * V (shuffles inlined, transient)
  f32x16 o0, o1;
#pragma unroll
  for (int r = 0; r < 16; ++r) { o0[r] = 0.0f; o1[r] = 0.0f; }
#pragma unroll
  for (int kk = 0; kk < 2; ++kk) {
    const unsigned ps0 = __shfl_xor(PP[4 * kk + 0], 32);
    const unsigned ps1 = __shfl_xor(PP[4 * kk + 1], 32);
    const unsigned ps2 = __shfl_xor(PP[4 * kk + 2], 32);
    const unsigned ps3 = __shfl_xor(PP[4 * kk + 3], 32);
    uint4 pa;
    pa.x = half ? ps2 : PP[4 * kk + 0];
    pa.y = half ? ps3 : PP[4 * kk + 1];
    pa.z = half ? PP[4 * kk + 2] : ps0;
    pa.w = half ? PP[4 * kk + 3] : ps1;

    const unsigned vs00 = __shfl_xor(VP[0][4 * kk + 0], 32);
    const unsigned vs01 = __shfl_xor(VP[0][4 * kk + 1], 32);
    const unsigned vs02 = __shfl_xor(VP[0][4 * kk + 2], 32);
    const unsigned vs03 = __shfl_xor(VP[0][4 * kk + 3], 32);
    uint4 vb0;
    vb0.x = half ? vs02 : VP[0][4 * kk + 0];
    vb0.y = half ? vs03 : VP[0][4 * kk + 1];
    vb0.z = half ? VP[0][4 * kk + 2] : vs00;
    vb0.w = half ? VP[0][4 * kk + 3] : vs01;

    const unsigned vs10 = __shfl_xor(VP[1][4 * kk + 0], 32);
    const unsigned vs11 = __shfl_xor(VP[1][4 * kk + 1], 32);
    const unsigned vs12 = __shfl_xor(VP[1][4 * kk + 2], 32);
    const unsigned vs13 = __shfl_xor(VP[1][4 * kk + 3], 32);
    uint4 vb1;
    vb1.x = half ? vs12 : VP[1][4 * kk + 0];
    vb1.y = half ? vs13 : VP[1][4 * kk + 1];
    vb1.z = half ? VP[1][4 * kk + 2] : vs10;
    vb1.w = half ? VP[1][4 * kk + 3] : vs11;

    o0 = mfma32(pa, vb0, o0);
    o1 = mfma32(pa, vb1, o1);
  }

  // output: lane col d = t*32+l31 of head h, rows n in regs (128B/half coalesced)
  float* obase = out_attn + (size_t)bs * NBD + h * 64 + l31;
#pragma unroll
  for (int r = 0; r < 16; ++r) {
    const int n = (r & 3) + 8 * (r >> 2) + 4 * half;
    obase[n * 512] = o0[r];
    obase[n * 512 + 32] = o1[r];
  }
}

extern "C" void kernel_launch(void* const* d_in, const int* in_sizes, int n_in,
                              void* d_out, int out_size, void* d_ws, size_t ws_size,
                              hipStream_t stream) {
  const float* q    = (const float*)d_in[0];
  const float* k    = (const float*)d_in[1];
  const float* v    = (const float*)d_in[2];
  const float* mask = (const float*)d_in[3];
  const float* wq   = (const float*)d_in[4];
  const float* bq   = (const float*)d_in[5];
  const float* wk   = (const float*)d_in[6];
  const float* bk   = (const float*)d_in[7];
  const float* wv   = (const float*)d_in[8];
  const float* bv   = (const float*)d_in[9];

  unsigned short* wbf = (unsigned short*)d_ws;  // 3*512*512 bf16 = 1.5 MB
  float* out_attn = (float*)d_out;
  float* out_w = out_attn + (size_t)4 * 512 * 32 * 512;

  wconv_kernel<<<256, 256, 0, stream>>>(wq, wk, wv, wbf);
  mhba_kernel<<<2048, 512, 0, stream>>>(q, k, v, mask, bq, bk, bv, wbf,
                                        out_attn, out_w);
}

// Round 4
// 363.353 us; speedup vs baseline: 1.5243x; 1.2640x over previous
//
#include <hip/hip_runtime.h>
#include <hip/hip_bf16.h>

// MultiheadBlockAttention: B=4, S=512, NB=32, D=512, H=8, dh=64.
// One WG (8 waves) per (b,s); wave h == head h end-to-end.
// R4 changes vs R3 (which stalled on 32-line gather weight loads, MfmaUtil 9%):
//   - wconv packs weights FRAGMENT-MAJOR: each (tile,kstep,half,lane) uint4 is
//     consecutive -> every weight load is one coalesced 1KB stream access.
//   - t=0/t=1 column tiles merged in one k-loop: X fragment shared, 2
//     independent MFMA chains (ILP), half the ds_reads.
//   - Q,K projections computed TRANSPOSED (swap mfma operands; same fragments)
//     so S^T operands come from registers via shfl_xor+cndmask conversion —
//     no LDS scratch transposes for Q/K at all.
//   - LDS scratch only for coalescing out_w (per-wave f32, stride 33).

#define NBD (32 * 512)
#define XS_STRIDE 516  // shorts per X row = 1032 B (dword stride % 32 == 2)

typedef __bf16 bf16x8 __attribute__((ext_vector_type(8)));
typedef float f32x16 __attribute__((ext_vector_type(16)));

__device__ __forceinline__ unsigned f2b(float f) {
  union { float f; unsigned u; } v;
  v.f = f;
  return (v.u + 0x7fffu + ((v.u >> 16) & 1u)) >> 16;
}

__device__ __forceinline__ f32x16 mfma32(uint4 a, uint4 b, f32x16 c) {
  union { uint4 u; bf16x8 v; } ua, ub;
  ua.u = a;
  ub.u = b;
  return __builtin_amdgcn_mfma_f32_32x32x16_bf16(ua.v, ub.v, c, 0, 0, 0);
}

// two ds_read_b64 (8-aligned base)
__device__ __forceinline__ uint4 ld_lds_64x2(const unsigned short* p, unsigned byteoff) {
  const char* c = (const char*)p;
  uint2 lo = *(const uint2*)(c + byteoff);
  uint2 hi = *(const uint2*)(c + byteoff + 8);
  uint4 r;
  r.x = lo.x; r.y = lo.y; r.z = hi.x; r.w = hi.y;
  return r;
}

// C/D packed frag (pairs at {0,1},{2,3},{8,9},{10,11},{16,..},..+4*half) ->
// A/B-frag k-slice [qb-block]: cross-half exchange + select. (R3-verified.)
__device__ __forceinline__ uint4 frag_cd(const unsigned* CP, int qb, int half) {
  const unsigned s0 = __shfl_xor(CP[qb + 0], 32);
  const unsigned s1 = __shfl_xor(CP[qb + 1], 32);
  const unsigned s2 = __shfl_xor(CP[qb + 2], 32);
  const unsigned s3 = __shfl_xor(CP[qb + 3], 32);
  uint4 f;
  f.x = half ? s2 : CP[qb + 0];
  f.y = half ? s3 : CP[qb + 1];
  f.z = half ? CP[qb + 2] : s0;
  f.w = half ? CP[qb + 3] : s1;
  return f;
}

// Pack wq|wk|wv into fragment-major bf16: uint4 index
//   m*32768 + tile*2048 + k*64 + half*32 + l31
// holds W[tile*32+l31][k*16+half*8 .. +7].
__global__ void wconv_kernel(const float* __restrict__ wq,
                             const float* __restrict__ wk,
                             const float* __restrict__ wv,
                             uint4* __restrict__ out) {
  const int g = blockIdx.x * blockDim.x + threadIdx.x;  // 0..98303
  const int m = g >> 15;
  const int j = g & 32767;
  const int l31 = j & 31;
  const int half = (j >> 5) & 1;
  const int k = (j >> 6) & 31;
  const int tile = j >> 11;  // 0..15
  const float* src = (m == 0) ? wq : (m == 1) ? wk : wv;
  const float4* p = (const float4*)(src + (size_t)(tile * 32 + l31) * 512 + k * 16 + half * 8);
  float4 f0 = p[0], f1 = p[1];
  uint4 o;
  o.x = f2b(f0.x) | (f2b(f0.y) << 16);
  o.y = f2b(f0.z) | (f2b(f0.w) << 16);
  o.z = f2b(f1.x) | (f2b(f1.y) << 16);
  o.w = f2b(f1.z) | (f2b(f1.w) << 16);
  out[g] = o;
}

__global__ __launch_bounds__(512, 4)
void mhba_kernel(const float* __restrict__ q_in, const float* __restrict__ k_in,
                 const float* __restrict__ v_in, const float* __restrict__ mask,
                 const float* __restrict__ bq, const float* __restrict__ bk,
                 const float* __restrict__ bv,
                 const uint4* __restrict__ wpk,   // fragment-major bf16 weights
                 float* __restrict__ out_attn,    // [B,S,NB,D]
                 float* __restrict__ out_w) {     // [B,H,S,NB,NB]
  __shared__ unsigned short Xs[32 * XS_STRIDE];  // 33024 B
  __shared__ float SCRF[8][32 * 33];             // 33792 B (out_w transpose)

  const int bs = blockIdx.x;    // b = bs>>9, s = bs&511
  const int tid = threadIdx.x;  // 0..511
  const int lane = tid & 63;
  const int h = tid >> 6;       // wave == head
  const int l31 = lane & 31;
  const int half = lane >> 5;

  const float* srcG[3] = {q_in, k_in, v_in};

  // Packed bf16 C/D fragments (all lane-local):
  //  QT/KT: transposed proj -> lane = token, regs = features (per t-tile)
  //  VP   : normal proj     -> lane = feature col, regs = token rows
  unsigned QT[2][8], KT[2][8], VP[2][8];

  // ---------------- projections (m: 0=Q^T, 1=K^T, 2=V) ----------------
#pragma unroll
  for (int m = 0; m < 3; ++m) {
    __syncthreads();  // protect Xs from previous iteration's readers
    const float4* src4 = (const float4*)(srcG[m] + (size_t)bs * NBD);
#pragma unroll
    for (int i = 0; i < 8; ++i) {
      const int idx4 = i * 512 + tid;  // 128 float4 per row
      float4 f = src4[idx4];
      const int n = idx4 >> 7;
      const int k4 = idx4 & 127;
      uint2 u;
      u.x = f2b(f.x) | (f2b(f.y) << 16);
      u.y = f2b(f.z) | (f2b(f.w) << 16);
      *(uint2*)((char*)Xs + (n * (XS_STRIDE * 2) + k4 * 8)) = u;
    }
    __syncthreads();

    // coalesced fragment-major weight streams for tiles 2h, 2h+1
    const uint4* w0 = wpk + m * 32768 + (2 * h) * 2048 + half * 32 + l31;
    const uint4* w1 = w0 + 2048;
    const unsigned abase = (unsigned)(l31 * (XS_STRIDE * 2) + half * 16);

    f32x16 acc0, acc1;
#pragma unroll
    for (int r = 0; r < 16; ++r) { acc0[r] = 0.0f; acc1[r] = 0.0f; }
#pragma unroll 8
    for (int k = 0; k < 32; ++k) {
      uint4 a = ld_lds_64x2(Xs, abase + (unsigned)k * 32);
      uint4 b0 = w0[k * 64];
      uint4 b1 = w1[k * 64];
      if (m <= 1) {  // transposed: A = W-tile (features->regs), B = X (tokens->lanes)
        acc0 = mfma32(b0, a, acc0);
        acc1 = mfma32(b1, a, acc1);
      } else {       // normal: A = X (tokens->regs), B = W (features->lanes)
        acc0 = mfma32(a, b0, acc0);
        acc1 = mfma32(a, b1, acc1);
      }
    }

    if (m == 0) {
#pragma unroll
      for (int q = 0; q < 8; ++q) {
        const int n0 = ((2 * q) & 3) + 8 * (q >> 1) + 4 * half;  // feature idx
        float2 bv0 = *(const float2*)(bq + h * 64 + n0);
        float2 bv1 = *(const float2*)(bq + h * 64 + 32 + n0);
        QT[0][q] = f2b(acc0[2 * q] + bv0.x) | (f2b(acc0[2 * q + 1] + bv0.y) << 16);
        QT[1][q] = f2b(acc1[2 * q] + bv1.x) | (f2b(acc1[2 * q + 1] + bv1.y) << 16);
      }
    } else if (m == 1) {
#pragma unroll
      for (int q = 0; q < 8; ++q) {
        const int n0 = ((2 * q) & 3) + 8 * (q >> 1) + 4 * half;
        float2 bv0 = *(const float2*)(bk + h * 64 + n0);
        float2 bv1 = *(const float2*)(bk + h * 64 + 32 + n0);
        KT[0][q] = f2b(acc0[2 * q] + bv0.x) | (f2b(acc0[2 * q + 1] + bv0.y) << 16);
        KT[1][q] = f2b(acc1[2 * q] + bv1.x) | (f2b(acc1[2 * q + 1] + bv1.y) << 16);
      }
    } else {
      const float bc0 = bv[h * 64 + l31];
      const float bc1 = bv[h * 64 + 32 + l31];
#pragma unroll
      for (int q = 0; q < 8; ++q) {
        VP[0][q] = f2b(acc0[2 * q] + bc0) | (f2b(acc0[2 * q + 1] + bc0) << 16);
        VP[1][q] = f2b(acc1[2 * q] + bc1) | (f2b(acc1[2 * q + 1] + bc1) << 16);
      }
    }
  }

  // ---------------- attention (barrier-free, per-wave) ----------------
  // S^T = K * Q^T : A-frag from KT, B-frag from QT (register conversions)
  f32x16 lg;
#pragma unroll
  for (int r = 0; r < 16; ++r) lg[r] = 0.0f;
#pragma unroll
  for (int kk = 0; kk < 4; ++kk) {
    const int t = kk >> 1, qb = (kk & 1) * 4;
    uint4 ka = frag_cd(KT[t], qb, half);
    uint4 qf = frag_cd(QT[t], qb, half);
    lg = mfma32(ka, qf, lg);
  }

  // softmax over keys m (16 regs + cross-half), additive mask[m]
  const float4* mask4 = (const float4*)(mask + (size_t)bs * 32);
  float4 mk4[4];
#pragma unroll
  for (int q = 0; q < 4; ++q) mk4[q] = mask4[2 * q + half];
  float x[16];
#pragma unroll
  for (int r = 0; r < 16; ++r) {
    const float* mkp = (const float*)&mk4[r >> 2];
    x[r] = lg[r] * 0.125f + mkp[r & 3];
  }
  float mx = x[0];
#pragma unroll
  for (int r = 1; r < 16; ++r) mx = fmaxf(mx, x[r]);
  mx = fmaxf(mx, __shfl_xor(mx, 32));
  float w[16], ss = 0.0f;
#pragma unroll
  for (int r = 0; r < 16; ++r) {
    w[r] = __expf(x[r] - mx);
    ss += w[r];
  }
  ss += __shfl_xor(ss, 32);
  const float inv = __frcp_rn(ss);
#pragma unroll
  for (int r = 0; r < 16; ++r) w[r] *= inv;

  // pack P (lane = query n, pairs of key rows)
  unsigned PP[8];
#pragma unroll
  for (int q = 0; q < 8; ++q)
    PP[q] = f2b(w[2 * q]) | (f2b(w[2 * q + 1]) << 16);

  // out_w: transpose through per-wave f32 scratch -> 256B-coalesced stores
  float* scrF = &SCRF[h][0];
#pragma unroll
  for (int r = 0; r < 16; ++r) {
    const int mm = (r & 3) + 8 * (r >> 2) + 4 * half;
    scrF[l31 * 33 + mm] = w[r];  // [query n=l31][key mm]
  }
  const int b = bs >> 9;
  const int s = bs & 511;
  float* wout = out_w + ((size_t)((b * 8 + h) * 512 + s)) * 1024;
#pragma unroll
  for (int j = 0; j < 16; ++j) {
    const int n = 2 * j + half;
    wout[n * 32 + l31] = scrF[n * 33 + l31];
  }

  // O = P * V
  f32x16 o0, o1;
#pragma unroll
  for (int r = 0; r < 16; ++r) { o0[r] = 0.0f; o1[r] = 0.0f; }
#pragma unroll
  for (int kk = 0; kk < 2; ++kk) {
    uint4 pa = frag_cd(PP, 4 * kk, half);
    uint4 vb0 = frag_cd(VP[0], 4 * kk, half);
    uint4 vb1 = frag_cd(VP[1], 4 * kk, half);
    o0 = mfma32(pa, vb0, o0);
    o1 = mfma32(pa, vb1, o1);
  }

  // output: lane col d = t*32+l31 of head h, rows n in regs
  float* obase = out_attn + (size_t)bs * NBD + h * 64 + l31;
#pragma unroll
  for (int r = 0; r < 16; ++r) {
    const int n = (r & 3) + 8 * (r >> 2) + 4 * half;
    obase[n * 512] = o0[r];
    obase[n * 512 + 32] = o1[r];
  }
}

extern "C" void kernel_launch(void* const* d_in, const int* in_sizes, int n_in,
                              void* d_out, int out_size, void* d_ws, size_t ws_size,
                              hipStream_t stream) {
  const float* q    = (const float*)d_in[0];
  const float* k    = (const float*)d_in[1];
  const float* v    = (const float*)d_in[2];
  const float* mask = (const float*)d_in[3];
  const float* wq   = (const float*)d_in[4];
  const float* bq   = (const float*)d_in[5];
  const float* wk   = (const float*)d_in[6];
  const float* bk   = (const float*)d_in[7];
  const float* wv   = (const float*)d_in[8];
  const float* bv   = (const float*)d_in[9];

  uint4* wpk = (uint4*)d_ws;  // 3*32768 uint4 = 1.5 MB fragment-major weights
  float* out_attn = (float*)d_out;
  float* out_w = out_attn + (size_t)4 * 512 * 32 * 512;

  wconv_kernel<<<384, 256, 0, stream>>>(wq, wk, wv, wpk);
  mhba_kernel<<<2048, 512, 0, stream>>>(q, k, v, mask, bq, bk, bv, wpk,
                                        out_attn, out_w);
}

// Round 5
// 234.773 us; speedup vs baseline: 2.3591x; 1.5477x over previous
//
#include <hip/hip_runtime.h>
#include <hip/hip_bf16.h>

// MultiheadBlockAttention: B=4, S=512, NB=32, D=512, H=8, dh=64.
// One WG (8 waves) per (b,s); wave h == head h end-to-end.
// R5 vs R4 (which spilled ~405MB scratch at the 128-reg unified cap):
//   - projections reordered K -> Q -> V; K (normal mode) goes straight to a
//     per-wave 4KB swizzled LDS buffer (never held in registers)
//   - softmax logits masked/exponentiated in place (x[] folded into w[])
//   - mask loaded as transient float2 pairs inside the loop
//   peak live regs ~110 < 128 -> no spills at 2 WG/CU occupancy.

#define NBD (32 * 512)
#define XS_STRIDE 516  // shorts per X row = 1032 B (2-way on b64 reads = free)

typedef __bf16 bf16x8 __attribute__((ext_vector_type(8)));
typedef float f32x16 __attribute__((ext_vector_type(16)));

__device__ __forceinline__ unsigned f2b(float f) {
  union { float f; unsigned u; } v;
  v.f = f;
  return (v.u + 0x7fffu + ((v.u >> 16) & 1u)) >> 16;
}

__device__ __forceinline__ f32x16 mfma32(uint4 a, uint4 b, f32x16 c) {
  union { uint4 u; bf16x8 v; } ua, ub;
  ua.u = a;
  ub.u = b;
  return __builtin_amdgcn_mfma_f32_32x32x16_bf16(ua.v, ub.v, c, 0, 0, 0);
}

// two ds_read_b64 (8-aligned base)
__device__ __forceinline__ uint4 ld_lds_64x2(const unsigned short* p, unsigned byteoff) {
  const char* c = (const char*)p;
  uint2 lo = *(const uint2*)(c + byteoff);
  uint2 hi = *(const uint2*)(c + byteoff + 8);
  uint4 r;
  r.x = lo.x; r.y = lo.y; r.z = hi.x; r.w = hi.y;
  return r;
}

// C/D packed frag -> A/B-frag k-slice [qb block]: cross-half exchange + select.
__device__ __forceinline__ uint4 frag_cd(const unsigned* CP, int qb, int half) {
  const unsigned s0 = __shfl_xor(CP[qb + 0], 32);
  const unsigned s1 = __shfl_xor(CP[qb + 1], 32);
  const unsigned s2 = __shfl_xor(CP[qb + 2], 32);
  const unsigned s3 = __shfl_xor(CP[qb + 3], 32);
  uint4 f;
  f.x = half ? s2 : CP[qb + 0];
  f.y = half ? s3 : CP[qb + 1];
  f.z = half ? CP[qb + 2] : s0;
  f.w = half ? CP[qb + 3] : s1;
  return f;
}

// Pack wq|wk|wv fragment-major bf16: uint4 index
//   m*32768 + tile*2048 + k*64 + half*32 + l31  holds W[tile*32+l31][k*16+half*8..+7]
__global__ void wconv_kernel(const float* __restrict__ wq,
                             const float* __restrict__ wk,
                             const float* __restrict__ wv,
                             uint4* __restrict__ out) {
  const int g = blockIdx.x * blockDim.x + threadIdx.x;  // 0..98303
  const int m = g >> 15;
  const int j = g & 32767;
  const int l31 = j & 31;
  const int half = (j >> 5) & 1;
  const int k = (j >> 6) & 31;
  const int tile = j >> 11;  // 0..15
  const float* src = (m == 0) ? wq : (m == 1) ? wk : wv;
  const float4* p = (const float4*)(src + (size_t)(tile * 32 + l31) * 512 + k * 16 + half * 8);
  float4 f0 = p[0], f1 = p[1];
  uint4 o;
  o.x = f2b(f0.x) | (f2b(f0.y) << 16);
  o.y = f2b(f0.z) | (f2b(f0.w) << 16);
  o.z = f2b(f1.x) | (f2b(f1.y) << 16);
  o.w = f2b(f1.z) | (f2b(f1.w) << 16);
  out[g] = o;
}

__global__ __launch_bounds__(512, 4)
void mhba_kernel(const float* __restrict__ q_in, const float* __restrict__ k_in,
                 const float* __restrict__ v_in, const float* __restrict__ mask,
                 const float* __restrict__ bq, const float* __restrict__ bk,
                 const float* __restrict__ bv,
                 const uint4* __restrict__ wpk,   // fragment-major bf16 weights
                 float* __restrict__ out_attn,    // [B,S,NB,D]
                 float* __restrict__ out_w) {     // [B,H,S,NB,NB]
  __shared__ unsigned short Xs[32 * XS_STRIDE];     // 33024 B
  __shared__ __align__(16) char SCR[8][4352];       // 34816 B per-wave scratch

  const int bs = blockIdx.x;    // b = bs>>9, s = bs&511
  const int tid = threadIdx.x;  // 0..511
  const int lane = tid & 63;
  const int h = tid >> 6;       // wave == head
  const int l31 = lane & 31;
  const int half = lane >> 5;

  // m-loop: 0 = K (normal -> LDS), 1 = Q (transposed -> regs), 2 = V (normal -> regs)
  const float* srcG[3] = {k_in, q_in, v_in};
  char* scr = &SCR[h][0];

  unsigned QT[2][8], VP[2][8];

  // ---------------- projections ----------------
#pragma unroll
  for (int m = 0; m < 3; ++m) {
    __syncthreads();  // protect Xs from previous iteration's readers
    const float4* src4 = (const float4*)(srcG[m] + (size_t)bs * NBD);
#pragma unroll
    for (int i = 0; i < 8; ++i) {
      const int idx4 = i * 512 + tid;  // 128 float4 per row
      float4 f = src4[idx4];
      const int n = idx4 >> 7;
      const int k4 = idx4 & 127;
      uint2 u;
      u.x = f2b(f.x) | (f2b(f.y) << 16);
      u.y = f2b(f.z) | (f2b(f.w) << 16);
      *(uint2*)((char*)Xs + (n * (XS_STRIDE * 2) + k4 * 8)) = u;
    }
    __syncthreads();

    // coalesced fragment-major weight streams for tiles 2h, 2h+1
    const int wsel = (m == 0) ? 1 : (m == 1) ? 0 : 2;  // K<-wk, Q<-wq, V<-wv
    const uint4* w0 = wpk + wsel * 32768 + (2 * h) * 2048 + half * 32 + l31;
    const uint4* w1 = w0 + 2048;
    const unsigned abase = (unsigned)(l31 * (XS_STRIDE * 2) + half * 16);

    f32x16 acc0, acc1;
#pragma unroll
    for (int r = 0; r < 16; ++r) { acc0[r] = 0.0f; acc1[r] = 0.0f; }
#pragma unroll 8
    for (int k = 0; k < 32; ++k) {
      uint4 a = ld_lds_64x2(Xs, abase + (unsigned)k * 32);
      uint4 b0 = w0[k * 64];
      uint4 b1 = w1[k * 64];
      if (m == 1) {  // transposed: A = W (features->regs), B = X (tokens->lanes)
        acc0 = mfma32(b0, a, acc0);
        acc1 = mfma32(b1, a, acc1);
      } else {       // normal: A = X (tokens->regs), B = W (features->lanes)
        acc0 = mfma32(a, b0, acc0);
        acc1 = mfma32(a, b1, acc1);
      }
    }

    if (m == 0) {
      // K -> per-wave LDS [token row n][feature f], row 128B, XOR ((n&7)<<4)
      const float bc0 = bk[h * 64 + l31];
      const float bc1 = bk[h * 64 + 32 + l31];
#pragma unroll
      for (int r = 0; r < 16; ++r) {
        const int n = (r & 3) + 8 * (r >> 2) + 4 * half;
        const unsigned base = (unsigned)(n * 128);
        const unsigned sw = (unsigned)(n & 7) << 4;
        *(unsigned short*)(scr + ((base + l31 * 2) ^ sw)) =
            (unsigned short)f2b(acc0[r] + bc0);
        *(unsigned short*)(scr + ((base + 64 + l31 * 2) ^ sw)) =
            (unsigned short)f2b(acc1[r] + bc1);
      }
    } else if (m == 1) {
      // Q^T: lane = token, regs = features
#pragma unroll
      for (int q = 0; q < 8; ++q) {
        const int n0 = ((2 * q) & 3) + 8 * (q >> 1) + 4 * half;  // feature idx
        float2 bv0 = *(const float2*)(bq + h * 64 + n0);
        float2 bv1 = *(const float2*)(bq + h * 64 + 32 + n0);
        QT[0][q] = f2b(acc0[2 * q] + bv0.x) | (f2b(acc0[2 * q + 1] + bv0.y) << 16);
        QT[1][q] = f2b(acc1[2 * q] + bv1.x) | (f2b(acc1[2 * q + 1] + bv1.y) << 16);
      }
    } else {
      const float bc0 = bv[h * 64 + l31];
      const float bc1 = bv[h * 64 + 32 + l31];
#pragma unroll
      for (int q = 0; q < 8; ++q) {
        VP[0][q] = f2b(acc0[2 * q] + bc0) | (f2b(acc0[2 * q + 1] + bc0) << 16);
        VP[1][q] = f2b(acc1[2 * q] + bc1) | (f2b(acc1[2 * q + 1] + bc1) << 16);
      }
    }
  }

  // ---------------- attention (barrier-free, per-wave) ----------------
  // S^T = K * Q^T : A-frag = K row l31 from LDS, B-frag = QT regs
  f32x16 lg;
#pragma unroll
  for (int r = 0; r < 16; ++r) lg[r] = 0.0f;
#pragma unroll
  for (int kk = 0; kk < 4; ++kk) {
    const unsigned off =
        (unsigned)(l31 * 128 + kk * 32 + half * 16) ^ ((unsigned)(l31 & 7) << 4);
    uint4 ka = *(const uint4*)(scr + off);
    uint4 qf = frag_cd(QT[kk >> 1], (kk & 1) * 4, half);
    lg = mfma32(ka, qf, lg);
  }

  // softmax over keys m, in place (lane = query n, regs = key m)
  const float* mrow = mask + (size_t)bs * 32;
  float w[16];
#pragma unroll
  for (int q = 0; q < 8; ++q) {
    const int mm0 = ((2 * q) & 3) + 8 * (q >> 1) + 4 * half;
    float2 mk = *(const float2*)(mrow + mm0);
    w[2 * q] = lg[2 * q] * 0.125f + mk.x;
    w[2 * q + 1] = lg[2 * q + 1] * 0.125f + mk.y;
  }
  float mx = w[0];
#pragma unroll
  for (int r = 1; r < 16; ++r) mx = fmaxf(mx, w[r]);
  mx = fmaxf(mx, __shfl_xor(mx, 32));
  float ss = 0.0f;
#pragma unroll
  for (int r = 0; r < 16; ++r) {
    w[r] = __expf(w[r] - mx);
    ss += w[r];
  }
  ss += __shfl_xor(ss, 32);
  const float inv = __frcp_rn(ss);
#pragma unroll
  for (int r = 0; r < 16; ++r) w[r] *= inv;

  // pack P (lane = query n, reg pairs = key rows)
  unsigned PP[8];
#pragma unroll
  for (int q = 0; q < 8; ++q)
    PP[q] = f2b(w[2 * q]) | (f2b(w[2 * q + 1]) << 16);

  // out_w: transpose through per-wave scratch (f32 view; K-buf is dead now,
  // all its reads feed lg -> w by data dependence) -> 256B-coalesced stores
  float* scrF = (float*)scr;  // 32 x 33 floats = 4224 B
#pragma unroll
  for (int r = 0; r < 16; ++r) {
    const int mm = (r & 3) + 8 * (r >> 2) + 4 * half;
    scrF[l31 * 33 + mm] = w[r];  // [query n=l31][key mm]
  }
  const int b = bs >> 9;
  const int s = bs & 511;
  float* wout = out_w + ((size_t)((b * 8 + h) * 512 + s)) * 1024;
#pragma unroll
  for (int j = 0; j < 16; ++j) {
    const int n = 2 * j + half;
    wout[n * 32 + l31] = scrF[n * 33 + l31];
  }

  // O = P * V
  f32x16 o0, o1;
#pragma unroll
  for (int r = 0; r < 16; ++r) { o0[r] = 0.0f; o1[r] = 0.0f; }
#pragma unroll
  for (int kk = 0; kk < 2; ++kk) {
    uint4 pa = frag_cd(PP, 4 * kk, half);
    uint4 vb0 = frag_cd(VP[0], 4 * kk, half);
    uint4 vb1 = frag_cd(VP[1], 4 * kk, half);
    o0 = mfma32(pa, vb0, o0);
    o1 = mfma32(pa, vb1, o1);
  }

  // output: lane col d = t*32+l31 of head h, rows n in regs
  float* obase = out_attn + (size_t)bs * NBD + h * 64 + l31;
#pragma unroll
  for (int r = 0; r < 16; ++r) {
    const int n = (r & 3) + 8 * (r >> 2) + 4 * half;
    obase[n * 512] = o0[r];
    obase[n * 512 + 32] = o1[r];
  }
}

extern "C" void kernel_launch(void* const* d_in, const int* in_sizes, int n_in,
                              void* d_out, int out_size, void* d_ws, size_t ws_size,
                              hipStream_t stream) {
  const float* q    = (const float*)d_in[0];
  const float* k    = (const float*)d_in[1];
  const float* v    = (const float*)d_in[2];
  const float* mask = (const float*)d_in[3];
  const float* wq   = (const float*)d_in[4];
  const float* bq   = (const float*)d_in[5];
  const float* wk   = (const float*)d_in[6];
  const float* bk   = (const float*)d_in[7];
  const float* wv   = (const float*)d_in[8];
  const float* bv   = (const float*)d_in[9];

  uint4* wpk = (uint4*)d_ws;  // 3*32768 uint4 = 1.5 MB fragment-major weights
  float* out_attn = (float*)d_out;
  float* out_w = out_attn + (size_t)4 * 512 * 32 * 512;

  wconv_kernel<<<384, 256, 0, stream>>>(wq, wk, wv, wpk);
  mhba_kernel<<<2048, 512, 0, stream>>>(q, k, v, mask, bq, bk, bv, wpk,
                                        out_attn, out_w);
}